// Round 8
// baseline (105.000 us; speedup 1.0000x reference)
//
#include <hip/hip_runtime.h>

// DendralNeuron: out[b,d] = min( min_f(x[b,f]-Wmin[d,f]), min_f(Wmax[d,f]-x[b,f]) )
// Tropical "min-GEMM". R11 vs R10 (42.7us, VALUBusy 75%, occupancy 30%):
// bounded SOFTWARE PIPELINE on the f-loop (T14 issue-early). Per f-step R10
// serially issued 8 broadcast x-loads (~150-300cyc L1/L2 latency) then 128
// dependent VALU ops; at ~2.4 waves/SIMD there is no TLP to hide the wait.
// R11 prefetches step fi+1's x-fragments into a second NAMED register set
// (xa/xb, static indexing -- rule #20) while computing step fi. Window is
// strictly 1 f-step (32 VGPR) -- NOT R9's unbounded hoist, which spilled.
//  - kept from R10: BM=128 x BN=32 (r=8,c=2), one-shot 56-feature W staging
//    (15.4KB LDS, LSTR=60 -> 2-way banks = free), ONE barrier per block,
//    grid 8x16x14 = 1792 blocks = 7/CU, merged accumulator.
//  - __launch_bounds__(256,2): R4 proved (256,4) squeezes to 64 VGPR+spills.
//  - pointer-advance addressing: bases += 32B/iter, loads use immediates.
// Decision rule: if dur is flat vs R10, latency was not binding -> VALU inst
// count is real bloat -> next round is disasm-driven inline asm.

constexpr int F_DIM = 784;
constexpr int BM = 128;
constexpr int BN = 32;
constexpr int ZSPLIT = 14;            // F-split: 56 features per z-slice
constexpr int FS = F_DIM / ZSPLIT;    // 56
constexpr int LSTR = 60;              // 240B rows: 16B-aligned, 2-way banks
constexpr int NF4 = FS / 4;           // 14 f4v steps per slice
constexpr int NIT = NF4 / 2;          // 7 pipelined double-steps

typedef float f4v __attribute__((ext_vector_type(4)));
typedef float f2v __attribute__((ext_vector_type(2)));

__global__ __launch_bounds__(256, 4)
void dendral_init_kernel(float* __restrict__ out) {
  const int i = blockIdx.x * 256 + threadIdx.x;
  const float inf = __builtin_inff();
  f4v v = {inf, inf, inf, inf};
  ((f4v*)out)[i] = v;
}

__device__ inline void atomic_min_float(float* addr, float v) {
  if (v >= 0.0f) atomicMin((int*)addr, __float_as_int(v));
  else           atomicMax((unsigned int*)addr, __float_as_uint(v));
}

// One (r,c) cell: 4 packed subs + 4 v_min3 folding 8 diffs + acc.
#define CELL(ACC, XV, NV, WV) do {                                   \
    f2v d1lo = (XV).xy - (NV).xy;                                    \
    f2v d1hi = (XV).zw - (NV).zw;                                    \
    f2v d2lo = (WV).xy - (XV).xy;                                    \
    f2v d2hi = (WV).zw - (XV).zw;                                    \
    float t1 = fminf(fminf(d1lo.x, d1lo.y), d1hi.x);                 \
    float t2 = fminf(fminf(d1hi.y, d2lo.x), d2lo.y);                 \
    float t3 = fminf(fminf(d2hi.x, d2hi.y), (ACC));                  \
    (ACC) = fminf(fminf(t1, t2), t3);                                \
  } while (0)

// One f-step (4 features, 16 outputs) using x-set XS at DS byte offset OFS.
#define FSTEP(XS, OFS) do {                                          \
    f4v nv0 = *(const f4v*)(ln0 + (OFS));                            \
    f4v nv1 = *(const f4v*)(ln1 + (OFS));                            \
    f4v wv0 = *(const f4v*)(lx0 + (OFS));                            \
    f4v wv1 = *(const f4v*)(lx1 + (OFS));                            \
    _Pragma("unroll")                                                \
    for (int r = 0; r < 8; ++r) {                                    \
      CELL(acc[r][0], XS[r], nv0, wv0);                              \
      CELL(acc[r][1], XS[r], nv1, wv1);                              \
    }                                                                \
  } while (0)

#define XLOAD(DST, OFS) do {                                         \
    _Pragma("unroll")                                                \
    for (int r = 0; r < 8; ++r)                                      \
      DST[r] = *(const f4v*)(xp[r] + (OFS));                         \
  } while (0)

__global__ __launch_bounds__(256, 2)
void dendral_min_kernel(const float* __restrict__ x,
                        const float* __restrict__ wmin,
                        const float* __restrict__ wmax,
                        float* __restrict__ out, int D) {
  __shared__ float lwn[BN * LSTR];    // wmin slice [32][60 (56 used)]
  __shared__ float lwx[BN * LSTR];    // wmax slice [32][60 (56 used)]

  const int t  = threadIdx.x;
  const int tx = t & 15;              // d-group: cols tx, tx+16
  const int ty = t >> 4;              // b-group: rows ty + 16r, r=0..7
  const int b0 = blockIdx.x * BM;
  const int d0 = blockIdx.y * BN;
  const int f0 = blockIdx.z * FS;     // feature-slice start

  // ---- Stage whole W slice: 64 rows (32 wmin + 32 wmax) x 14 f4v = 896.
#pragma unroll
  for (int k = 0; k < 4; ++k) {
    const int i = t + 256 * k;
    if (i < 64 * NF4) {
      const int row = i / NF4;        // 0..63
      const int c4  = i % NF4;        // 0..13
      const int wr  = row & 31;
      const float* src = (row < 32 ? wmin : wmax)
                         + (size_t)(d0 + wr) * F_DIM + f0 + c4 * 4;
      float* dst = (row < 32 ? lwn : lwx) + wr * LSTR + c4 * 4;
      *(f4v*)dst = *(const f4v*)src;
    }
  }
  __syncthreads();                    // the ONLY barrier

  float acc[8][2];
#pragma unroll
  for (int r = 0; r < 8; ++r)
#pragma unroll
    for (int c = 0; c < 2; ++c)
      acc[r][c] = __builtin_inff();

  // Rolling pointers: x row bases (broadcast loads, 16 lanes share addr)
  // and the 4 LDS fragment bases. Advance by 8 floats per double-step;
  // loads inside use small immediate offsets.
  const float* xp[8];
#pragma unroll
  for (int r = 0; r < 8; ++r)
    xp[r] = x + (size_t)(b0 + ty + 16 * r) * F_DIM + f0;
  const float* ln0 = &lwn[tx * LSTR];
  const float* ln1 = &lwn[(tx + 16) * LSTR];
  const float* lx0 = &lwx[tx * LSTR];
  const float* lx1 = &lwx[(tx + 16) * LSTR];

  f4v xa[8], xb[8];
  XLOAD(xa, 0);                       // prologue: fi=0 fragments

  for (int it = 0; it < NIT; ++it) {  // 7 double-steps, fi = 2*it
    XLOAD(xb, 4);                     // prefetch fi+1 while computing fi
    FSTEP(xa, 0);
    if (it + 1 < NIT)
      XLOAD(xa, 8);                   // prefetch fi+2 while computing fi+1
    FSTEP(xb, 4);
#pragma unroll
    for (int r = 0; r < 8; ++r)
      xp[r] += 8;
    ln0 += 8; ln1 += 8; lx0 += 8; lx1 += 8;
  }

  // Combine this z-slice's partial into out via device-scope atomic min.
#pragma unroll
  for (int r = 0; r < 8; ++r)
#pragma unroll
    for (int c = 0; c < 2; ++c) {
      const int b = b0 + ty + 16 * r;
      const int d = d0 + tx + 16 * c;
      atomic_min_float(&out[(size_t)b * D + d], acc[r][c]);
    }
}

extern "C" void kernel_launch(void* const* d_in, const int* in_sizes, int n_in,
                              void* d_out, int out_size, void* d_ws, size_t ws_size,
                              hipStream_t stream) {
  const float* x    = (const float*)d_in[0];
  const float* wmin = (const float*)d_in[1];
  const float* wmax = (const float*)d_in[2];
  float* out = (float*)d_out;
  const int B = in_sizes[0] / F_DIM;    // 1024 (element-count convention)
  const int D = in_sizes[1] / F_DIM;    // 512

  // Full-coverage init: B*D floats / (4 per thread * 256 threads) blocks.
  dendral_init_kernel<<<(B * D) / 1024, 256, 0, stream>>>(out);

  dim3 grid(B / BM, D / BN, ZSPLIT);    // 8 x 16 x 14 = 1792 blocks
  dendral_min_kernel<<<grid, 256, 0, stream>>>(x, wmin, wmax, out, D);
  (void)n_in; (void)d_ws; (void)ws_size; (void)out_size;
}

// Round 9
// 100.067 us; speedup vs baseline: 1.0493x; 1.0493x over previous
//
#include <hip/hip_runtime.h>

// DendralNeuron: out[b,d] = min( min_f(x[b,f]-Wmin[d,f]), min_f(Wmax[d,f]-x[b,f]) )
// Tropical "min-GEMM". R12 = R10 (42.7us, best) + INLINE-ASM inner cell.
// Rationale: VALU-busy time is invariant ~31us across R7/R8/R10/R11 despite
// halving LDS ops / removing barriers / zeroing addressing -> the bloat is in
// the MATH LOWERING. Force exactly 4x v_pk_add_f32 (packed sub via neg) +
// 4x v_min3_f32 per cell (8 insts per 4-feature cell = 2 VALU/triple floor).
// acc enters only the final min3 -> 1-min3 dependency chain per cell.
// R11 lesson: VGPR 60->76 cut resident blocks 7->6 on an exactly-7 grid
// (+17% = measured 49.6us). Constraint: VGPR must stay <= 64.
//  - kept from R10: BM=128 x BN=32 (r=8,c=2), one-shot 56-feature W staging
//    (15.4KB LDS, LSTR=60 -> 2-way banks, free), ONE barrier per block,
//    grid 8x16x14 = 1792 blocks = 7/CU, x via L1 broadcast global loads,
//    #pragma unroll 2 f-loop (NOT full unroll -- R9 spilled).
//  - __launch_bounds__(256,2): R4 proved (256,4) squeezes to 64 VGPR+spills.

constexpr int F_DIM = 784;
constexpr int BM = 128;
constexpr int BN = 32;
constexpr int ZSPLIT = 14;            // F-split: 56 features per z-slice
constexpr int FS = F_DIM / ZSPLIT;    // 56
constexpr int LSTR = 60;              // 240B rows: 16B-aligned, 2-way banks
constexpr int NF4 = FS / 4;           // 14 f4v steps per slice

typedef float f4v __attribute__((ext_vector_type(4)));
typedef float f2v __attribute__((ext_vector_type(2)));

__global__ __launch_bounds__(256, 4)
void dendral_init_kernel(float* __restrict__ out) {
  const int i = blockIdx.x * 256 + threadIdx.x;
  const float inf = __builtin_inff();
  f4v v = {inf, inf, inf, inf};
  ((f4v*)out)[i] = v;
}

__device__ inline void atomic_min_float(float* addr, float v) {
  if (v >= 0.0f) atomicMin((int*)addr, __float_as_int(v));
  else           atomicMax((unsigned int*)addr, __float_as_uint(v));
}

// One (r,c) cell over 4 features: guaranteed 4 v_pk_add_f32 + 4 v_min3_f32.
// d = x - w via pk_add with src1 negated (neg_lo/neg_hi on operand 1).
__device__ __forceinline__ void cell_min(float& acc, const f4v xv,
                                         const f4v nv, const f4v wv) {
  const f2v xlo = xv.xy, xhi = xv.zw;
  const f2v nlo = nv.xy, nhi = nv.zw;
  const f2v wlo = wv.xy, whi = wv.zw;
  f2v d0, d1, e0, e1;
  asm("v_pk_add_f32 %0, %1, %2 neg_lo:[0,1] neg_hi:[0,1]"
      : "=v"(d0) : "v"(xlo), "v"(nlo));            // x - wmin (lo pair)
  asm("v_pk_add_f32 %0, %1, %2 neg_lo:[0,1] neg_hi:[0,1]"
      : "=v"(d1) : "v"(xhi), "v"(nhi));            // x - wmin (hi pair)
  asm("v_pk_add_f32 %0, %1, %2 neg_lo:[0,1] neg_hi:[0,1]"
      : "=v"(e0) : "v"(wlo), "v"(xlo));            // wmax - x (lo pair)
  asm("v_pk_add_f32 %0, %1, %2 neg_lo:[0,1] neg_hi:[0,1]"
      : "=v"(e1) : "v"(whi), "v"(xhi));            // wmax - x (hi pair)
  float m0, m1, m2;
  asm("v_min3_f32 %0, %1, %2, %3"
      : "=v"(m0) : "v"(d0.x), "v"(d0.y), "v"(d1.x));
  asm("v_min3_f32 %0, %1, %2, %3"
      : "=v"(m1) : "v"(d1.y), "v"(e0.x), "v"(e0.y));
  asm("v_min3_f32 %0, %1, %2, %3"
      : "=v"(m2) : "v"(e1.x), "v"(e1.y), "v"(m0));
  asm("v_min3_f32 %0, %1, %2, %3"
      : "=v"(acc) : "v"(m1), "v"(m2), "v"(acc));   // acc only in last min3
}

__global__ __launch_bounds__(256, 2)
void dendral_min_kernel(const float* __restrict__ x,
                        const float* __restrict__ wmin,
                        const float* __restrict__ wmax,
                        float* __restrict__ out, int D) {
  __shared__ float lwn[BN * LSTR];    // wmin slice [32][60 (56 used)]
  __shared__ float lwx[BN * LSTR];    // wmax slice [32][60 (56 used)]

  const int t  = threadIdx.x;
  const int tx = t & 15;              // d-group: cols tx, tx+16
  const int ty = t >> 4;              // b-group: rows ty + 16r, r=0..7
  const int b0 = blockIdx.x * BM;
  const int d0 = blockIdx.y * BN;
  const int f0 = blockIdx.z * FS;     // feature-slice start

  // ---- Stage whole W slice: 64 rows (32 wmin + 32 wmax) x 14 f4v = 896.
#pragma unroll
  for (int k = 0; k < 4; ++k) {
    const int i = t + 256 * k;
    if (i < 64 * NF4) {
      const int row = i / NF4;        // 0..63
      const int c4  = i % NF4;        // 0..13
      const int wr  = row & 31;
      const float* src = (row < 32 ? wmin : wmax)
                         + (size_t)(d0 + wr) * F_DIM + f0 + c4 * 4;
      float* dst = (row < 32 ? lwn : lwx) + wr * LSTR + c4 * 4;
      *(f4v*)dst = *(const f4v*)src;
    }
  }
  __syncthreads();                    // the ONLY barrier

  // x row-base offset (VGPR, loop-invariant): row b0+ty, feature f0.
  const size_t xoff = (size_t)(b0 + ty) * F_DIM + f0;

  float acc[8][2];
#pragma unroll
  for (int r = 0; r < 8; ++r)
#pragma unroll
    for (int c = 0; c < 2; ++c)
      acc[r][c] = __builtin_inff();

  const float* lnb0 = &lwn[tx * LSTR];
  const float* lnb1 = &lwn[(tx + 16) * LSTR];
  const float* lwb0 = &lwx[tx * LSTR];
  const float* lwb1 = &lwx[(tx + 16) * LSTR];

#pragma unroll 2
  for (int fi = 0; fi < NF4; ++fi) {  // 14 f-steps of 4 features
    // x fragments: broadcast global loads (16 lanes share each address),
    // uniform base (r*16*F_DIM) + VGPR offset + fi*16B immediate.
    f4v xv[8];
#pragma unroll
    for (int r = 0; r < 8; ++r)
      xv[r] = *(const f4v*)(x + xoff + (size_t)r * 16 * F_DIM + fi * 4);
    // W fragments: 4 ds_read_b128, static addr + fi*16B immediate.
    f4v nv0 = *(const f4v*)(lnb0 + fi * 4);
    f4v nv1 = *(const f4v*)(lnb1 + fi * 4);
    f4v wv0 = *(const f4v*)(lwb0 + fi * 4);
    f4v wv1 = *(const f4v*)(lwb1 + fi * 4);
#pragma unroll
    for (int r = 0; r < 8; ++r) {
      cell_min(acc[r][0], xv[r], nv0, wv0);
      cell_min(acc[r][1], xv[r], nv1, wv1);
    }
  }

  // Combine this z-slice's partial into out via device-scope atomic min.
#pragma unroll
  for (int r = 0; r < 8; ++r)
#pragma unroll
    for (int c = 0; c < 2; ++c) {
      const int b = b0 + ty + 16 * r;
      const int d = d0 + tx + 16 * c;
      atomic_min_float(&out[(size_t)b * D + d], acc[r][c]);
    }
}

extern "C" void kernel_launch(void* const* d_in, const int* in_sizes, int n_in,
                              void* d_out, int out_size, void* d_ws, size_t ws_size,
                              hipStream_t stream) {
  const float* x    = (const float*)d_in[0];
  const float* wmin = (const float*)d_in[1];
  const float* wmax = (const float*)d_in[2];
  float* out = (float*)d_out;
  const int B = in_sizes[0] / F_DIM;    // 1024 (element-count convention)
  const int D = in_sizes[1] / F_DIM;    // 512

  // Full-coverage init: B*D floats / (4 per thread * 256 threads) blocks.
  dendral_init_kernel<<<(B * D) / 1024, 256, 0, stream>>>(out);

  dim3 grid(B / BM, D / BN, ZSPLIT);    // 8 x 16 x 14 = 1792 blocks
  dendral_min_kernel<<<grid, 256, 0, stream>>>(x, wmin, wmax, out, D);
  (void)n_in; (void)d_ws; (void)ws_size; (void)out_size;
}

// Round 10
// 98.179 us; speedup vs baseline: 1.0695x; 1.0192x over previous
//
#include <hip/hip_runtime.h>

// DendralNeuron: out[b,d] = min( min_f(x[b,f]-Wmin[d,f]), min_f(Wmax[d,f]-x[b,f]) )
// Tropical "min-GEMM". R13 = R12 with the ATOMIC EPILOGUE REPLACED by a
// two-phase scheme. Diagnosis chain: dur invariant ~43us while VALU-busy
// fell 32->22us (R12 asm) and LDS/barriers/x-latency were each exonerated
// (R10/R11). Invariant suspect: 7.34M device-scope atomicMin ops writing
// THROUGH to HBM every round (WRITE_SIZE == B*D*ZSPLIT*4B = 28.7MB, not the
// 2MB out buffer) -> memory-side RMW throughput ~24-37us, overlapping
// compute only partially -> dur = max(compute, atomics) ~= 43us.
// R13: phase 1 stores partials (plain coalesced stores) to d_ws[z][b*D+d]
// (29.4MB, ~5us); phase 2 reduces min over the 14 z-slices (~6us, HBM-bound).
// Init kernel eliminated. Fallback to R12's atomic path if ws too small.
//  - kept: BM=128 x BN=32 (r=8,c=2), one-shot 56-feature W staging (15.4KB
//    LDS, LSTR=60), ONE barrier, grid 8x16x14 = 1792 blocks = 7/CU,
//    x via L1 broadcast loads, #pragma unroll 2 f-loop (R9: full unroll
//    spills), inline-asm cell (4x v_pk_add_f32 + 4x v_min3_f32),
//    __launch_bounds__(256,2) (R4: (256,4) squeezes to 64 VGPR + spills),
//    VGPR must stay <=64 (R11: 76 VGPR -> 6/CU residency cliff).

constexpr int F_DIM = 784;
constexpr int BM = 128;
constexpr int BN = 32;
constexpr int ZSPLIT = 14;            // F-split: 56 features per z-slice
constexpr int FS = F_DIM / ZSPLIT;    // 56
constexpr int LSTR = 60;              // 240B rows: 16B-aligned, 2-way banks
constexpr int NF4 = FS / 4;           // 14 f4v steps per slice

typedef float f4v __attribute__((ext_vector_type(4)));
typedef float f2v __attribute__((ext_vector_type(2)));

__global__ __launch_bounds__(256, 4)
void dendral_init_kernel(float* __restrict__ out) {
  const int i = blockIdx.x * 256 + threadIdx.x;
  const float inf = __builtin_inff();
  f4v v = {inf, inf, inf, inf};
  ((f4v*)out)[i] = v;
}

__device__ inline void atomic_min_float(float* addr, float v) {
  if (v >= 0.0f) atomicMin((int*)addr, __float_as_int(v));
  else           atomicMax((unsigned int*)addr, __float_as_uint(v));
}

// One (r,c) cell over 4 features: guaranteed 4 v_pk_add_f32 + 4 v_min3_f32.
__device__ __forceinline__ void cell_min(float& acc, const f4v xv,
                                         const f4v nv, const f4v wv) {
  const f2v xlo = xv.xy, xhi = xv.zw;
  const f2v nlo = nv.xy, nhi = nv.zw;
  const f2v wlo = wv.xy, whi = wv.zw;
  f2v d0, d1, e0, e1;
  asm("v_pk_add_f32 %0, %1, %2 neg_lo:[0,1] neg_hi:[0,1]"
      : "=v"(d0) : "v"(xlo), "v"(nlo));            // x - wmin (lo pair)
  asm("v_pk_add_f32 %0, %1, %2 neg_lo:[0,1] neg_hi:[0,1]"
      : "=v"(d1) : "v"(xhi), "v"(nhi));            // x - wmin (hi pair)
  asm("v_pk_add_f32 %0, %1, %2 neg_lo:[0,1] neg_hi:[0,1]"
      : "=v"(e0) : "v"(wlo), "v"(xlo));            // wmax - x (lo pair)
  asm("v_pk_add_f32 %0, %1, %2 neg_lo:[0,1] neg_hi:[0,1]"
      : "=v"(e1) : "v"(whi), "v"(xhi));            // wmax - x (hi pair)
  float m0, m1, m2;
  asm("v_min3_f32 %0, %1, %2, %3"
      : "=v"(m0) : "v"(d0.x), "v"(d0.y), "v"(d1.x));
  asm("v_min3_f32 %0, %1, %2, %3"
      : "=v"(m1) : "v"(d1.y), "v"(e0.x), "v"(e0.y));
  asm("v_min3_f32 %0, %1, %2, %3"
      : "=v"(m2) : "v"(e1.x), "v"(e1.y), "v"(m0));
  asm("v_min3_f32 %0, %1, %2, %3"
      : "=v"(acc) : "v"(m1), "v"(m2), "v"(acc));   // acc only in last min3
}

// Shared body: compute acc[8][2] for this block's tile and z-slice.
template <bool USE_WS>
__device__ __forceinline__ void dendral_body(const float* __restrict__ x,
                                             const float* __restrict__ wmin,
                                             const float* __restrict__ wmax,
                                             float* __restrict__ dst,
                                             int D) {
  __shared__ float lwn[BN * LSTR];    // wmin slice [32][60 (56 used)]
  __shared__ float lwx[BN * LSTR];    // wmax slice [32][60 (56 used)]

  const int t  = threadIdx.x;
  const int tx = t & 15;              // d-group: cols tx, tx+16
  const int ty = t >> 4;              // b-group: rows ty + 16r, r=0..7
  const int b0 = blockIdx.x * BM;
  const int d0 = blockIdx.y * BN;
  const int f0 = blockIdx.z * FS;     // feature-slice start

  // ---- Stage whole W slice: 64 rows (32 wmin + 32 wmax) x 14 f4v = 896.
#pragma unroll
  for (int k = 0; k < 4; ++k) {
    const int i = t + 256 * k;
    if (i < 64 * NF4) {
      const int row = i / NF4;        // 0..63
      const int c4  = i % NF4;        // 0..13
      const int wr  = row & 31;
      const float* src = (row < 32 ? wmin : wmax)
                         + (size_t)(d0 + wr) * F_DIM + f0 + c4 * 4;
      float* d_ = (row < 32 ? lwn : lwx) + wr * LSTR + c4 * 4;
      *(f4v*)d_ = *(const f4v*)src;
    }
  }
  __syncthreads();                    // the ONLY barrier

  const size_t xoff = (size_t)(b0 + ty) * F_DIM + f0;

  float acc[8][2];
#pragma unroll
  for (int r = 0; r < 8; ++r)
#pragma unroll
    for (int c = 0; c < 2; ++c)
      acc[r][c] = __builtin_inff();

  const float* lnb0 = &lwn[tx * LSTR];
  const float* lnb1 = &lwn[(tx + 16) * LSTR];
  const float* lwb0 = &lwx[tx * LSTR];
  const float* lwb1 = &lwx[(tx + 16) * LSTR];

#pragma unroll 2
  for (int fi = 0; fi < NF4; ++fi) {  // 14 f-steps of 4 features
    f4v xv[8];
#pragma unroll
    for (int r = 0; r < 8; ++r)
      xv[r] = *(const f4v*)(x + xoff + (size_t)r * 16 * F_DIM + fi * 4);
    f4v nv0 = *(const f4v*)(lnb0 + fi * 4);
    f4v nv1 = *(const f4v*)(lnb1 + fi * 4);
    f4v wv0 = *(const f4v*)(lwb0 + fi * 4);
    f4v wv1 = *(const f4v*)(lwb1 + fi * 4);
#pragma unroll
    for (int r = 0; r < 8; ++r) {
      cell_min(acc[r][0], xv[r], nv0, wv0);
      cell_min(acc[r][1], xv[r], nv1, wv1);
    }
  }

  // Epilogue.
#pragma unroll
  for (int r = 0; r < 8; ++r)
#pragma unroll
    for (int c = 0; c < 2; ++c) {
      const int b = b0 + ty + 16 * r;
      const int d = d0 + tx + 16 * c;
      if (USE_WS)
        dst[(size_t)b * D + d] = acc[r][c];               // plain store
      else
        atomic_min_float(&dst[(size_t)b * D + d], acc[r][c]);
    }
}

__global__ __launch_bounds__(256, 2)
void dendral_part_kernel(const float* __restrict__ x,
                         const float* __restrict__ wmin,
                         const float* __restrict__ wmax,
                         float* __restrict__ ws, int D, int BD) {
  // partials laid out [z][b*D+d]; this block's slice base:
  float* dst = ws + (size_t)blockIdx.z * BD;
  dendral_body<true>(x, wmin, wmax, dst, D);
}

__global__ __launch_bounds__(256, 2)
void dendral_min_kernel(const float* __restrict__ x,
                        const float* __restrict__ wmin,
                        const float* __restrict__ wmax,
                        float* __restrict__ out, int D) {
  dendral_body<false>(x, wmin, wmax, out, D);
}

// Phase 2: out[i] = min_z ws[z][i], vectorized f4v, fully coalesced.
__global__ __launch_bounds__(256, 2)
void dendral_reduce_kernel(const float* __restrict__ ws,
                           float* __restrict__ out, int BD) {
  const int i4 = blockIdx.x * 256 + threadIdx.x;   // f4v index
  const f4v* w = (const f4v*)ws;
  const int n4 = BD >> 2;
  f4v m = w[i4];
#pragma unroll
  for (int z = 1; z < ZSPLIT; ++z) {
    f4v v = w[(size_t)z * n4 + i4];
    m.x = fminf(m.x, v.x);
    m.y = fminf(m.y, v.y);
    m.z = fminf(m.z, v.z);
    m.w = fminf(m.w, v.w);
  }
  ((f4v*)out)[i4] = m;
}

extern "C" void kernel_launch(void* const* d_in, const int* in_sizes, int n_in,
                              void* d_out, int out_size, void* d_ws, size_t ws_size,
                              hipStream_t stream) {
  const float* x    = (const float*)d_in[0];
  const float* wmin = (const float*)d_in[1];
  const float* wmax = (const float*)d_in[2];
  float* out = (float*)d_out;
  const int B = in_sizes[0] / F_DIM;    // 1024 (element-count convention)
  const int D = in_sizes[1] / F_DIM;    // 512
  const int BD = B * D;                 // 524288
  const size_t need = (size_t)BD * ZSPLIT * sizeof(float);  // 29.4 MB

  dim3 grid(B / BM, D / BN, ZSPLIT);    // 8 x 16 x 14 = 1792 blocks = 7/CU

  if (d_ws != nullptr && ws_size >= need) {
    // Two-phase: plain-store partials, then reduce. No init, no atomics.
    dendral_part_kernel<<<grid, 256, 0, stream>>>(x, wmin, wmax,
                                                  (float*)d_ws, D, BD);
    dendral_reduce_kernel<<<BD / 1024, 256, 0, stream>>>((const float*)d_ws,
                                                         out, BD);
  } else {
    // Fallback: R12's atomic path.
    dendral_init_kernel<<<BD / 1024, 256, 0, stream>>>(out);
    dendral_min_kernel<<<grid, 256, 0, stream>>>(x, wmin, wmax, out, D);
  }
  (void)n_in; (void)out_size;
}